// Round 6
// baseline (374.832 us; speedup 1.0000x reference)
//
#include <hip/hip_runtime.h>

// Problem constants (from reference)
constexpr int B = 256, L = 500, D = 3, C = 32, I = 35, H = 512, O = 15, M = 5, J = 35;
constexpr int KP1 = 64;  // k1 K-dim (I=35) zero-padded to 4 MFMA k-steps (32x32x16)
constexpr int JP = 48;   // out-cols padded to 3 MFMA n-tiles
constexpr int KPV = 520; // padded K leading dim for Vt
constexpr int NQ = 63;   // l-chunks (8 l each; last chunk has 4)
constexpr int NL = 8;    // l per chunk

typedef __attribute__((ext_vector_type(8))) _Float16 half8;  // MFMA A/B frag
typedef __attribute__((ext_vector_type(4))) float f32x4;     // 16x16 C/D frag
typedef __attribute__((ext_vector_type(16))) float f32x16;   // 32x32 C/D frag

// -------------------------------------------------------------------------
// k0x: xT[l][b][k] fp16, K padded to 64 (zeros k>=35).
// -------------------------------------------------------------------------
__global__ __launch_bounds__(256) void k0x(const float* __restrict__ inp,
                                           const float* __restrict__ z,
                                           _Float16* __restrict__ xT) {
  const int l = blockIdx.x, tid = threadIdx.x;  // tid = b
  __shared__ _Float16 xs[B][38];
  const float* ip = inp + ((size_t)tid * L + l) * D;
  const float4* zp = (const float4*)(z + ((size_t)tid * L + l) * C);
  xs[tid][0] = (_Float16)ip[0];
  xs[tid][1] = (_Float16)ip[1];
  xs[tid][2] = (_Float16)ip[2];
#pragma unroll
  for (int q = 0; q < 8; ++q) {
    float4 v = zp[q];
    xs[tid][D + q * 4 + 0] = (_Float16)v.x;
    xs[tid][D + q * 4 + 1] = (_Float16)v.y;
    xs[tid][D + q * 4 + 2] = (_Float16)v.z;
    xs[tid][D + q * 4 + 3] = (_Float16)v.w;
  }
  __syncthreads();
  unsigned int* dst = (unsigned int*)(xT + (size_t)l * B * KP1);
  for (int f = tid; f < B * KP1 / 2; f += 256) {
    int b = f >> 5, k = (f & 31) * 2;
    unsigned int lo = (k < I)     ? *(const unsigned short*)&xs[b][k]     : 0u;
    unsigned int hi = (k + 1 < I) ? *(const unsigned short*)&xs[b][k + 1] : 0u;
    dst[f] = lo | (hi << 16);
  }
}

// -------------------------------------------------------------------------
// k0w: Wt[l][h][k] fp16 (K padded 64) from W_enc fp32 [l][i][h] (transpose).
// -------------------------------------------------------------------------
__global__ __launch_bounds__(256) void k0w(const float* __restrict__ W,
                                           _Float16* __restrict__ Wt) {
  const int l = blockIdx.x, tid = threadIdx.x;
  __shared__ _Float16 ws[H][37];
  for (int f = tid; f < I * H; f += 256) {
    int i = f >> 9, h = f & 511;
    ws[h][i] = (_Float16)W[((size_t)l * I + i) * H + h];
  }
  __syncthreads();
  unsigned int* dst = (unsigned int*)(Wt + (size_t)l * H * KP1);
  for (int f = tid; f < H * KP1 / 2; f += 256) {
    int h = f >> 5, k = (f & 31) * 2;
    unsigned int lo = (k < I)     ? *(const unsigned short*)&ws[h][k]     : 0u;
    unsigned int hi = (k + 1 < I) ? *(const unsigned short*)&ws[h][k + 1] : 0u;
    dst[f] = lo | (hi << 16);
  }
}

// -------------------------------------------------------------------------
// k0v: Vt[l][j][k] fp16 [L][48][520]. LDS transpose, linear uint4 writes.
// -------------------------------------------------------------------------
__global__ __launch_bounds__(256) void k0v(const float* __restrict__ Vmu,
                                           const float* __restrict__ Vsg,
                                           const float* __restrict__ Vpi,
                                           _Float16* __restrict__ Vt) {
  const int l = blockIdx.x, tid = threadIdx.x;
  __shared__ __align__(16) _Float16 Vs[JP * KPV];  // 49,920 B
  for (int f = tid; f < (JP * KPV) / 8; f += 256) ((uint4*)Vs)[f] = (uint4){0, 0, 0, 0};
  __syncthreads();
  const float* vm = Vmu + (size_t)l * H * O;
  const float* vs = Vsg + (size_t)l * H * O;
  const float* vp = Vpi + (size_t)l * H * M;
  for (int idx = tid; idx < H * O; idx += 256) {
    int k = idx / O, j = idx - k * O;
    Vs[j * KPV + k]       = (_Float16)vm[idx];
    Vs[(O + j) * KPV + k] = (_Float16)vs[idx];
  }
  for (int idx = tid; idx < H * M; idx += 256) {
    int k = idx / M, j = idx - k * M;
    Vs[(2 * O + j) * KPV + k] = (_Float16)vp[idx];
  }
  __syncthreads();
  uint4* dst = (uint4*)(Vt + (size_t)l * JP * KPV);
  for (int f = tid; f < (JP * KPV) / 8; f += 256) dst[f] = ((const uint4*)Vs)[f];
}

// -------------------------------------------------------------------------
// k1: c[l,b,h] via 32x32x16 fp16 MFMA, no LDS, no barriers. (unchanged r5)
// -------------------------------------------------------------------------
__global__ __launch_bounds__(256, 4) void k1_c(const _Float16* __restrict__ xT,
                                               const _Float16* __restrict__ Wt,
                                               _Float16* __restrict__ cBH) {
  const int b0 = blockIdx.x * 128, h0 = blockIdx.y * 128, l = blockIdx.z;
  const int wave = threadIdx.x >> 6, lane = threadIdx.x & 63;
  const int ln31 = lane & 31, hi32 = lane >> 5;

  const _Float16* Ap = xT + ((size_t)l * B + b0 + wave * 32 + ln31) * KP1 + hi32 * 8;
  const _Float16* Bp = Wt + ((size_t)l * H + h0 + ln31) * KP1 + hi32 * 8;

  f32x16 acc[4];
#pragma unroll
  for (int nt = 0; nt < 4; ++nt)
#pragma unroll
    for (int r = 0; r < 16; ++r) acc[nt][r] = 0.f;

#pragma unroll
  for (int kt = 0; kt < 4; ++kt) {
    half8 a = *(const half8*)(Ap + kt * 16);
#pragma unroll
    for (int nt = 0; nt < 4; ++nt) {
      half8 bb = *(const half8*)(Bp + (size_t)nt * 32 * KP1 + kt * 16);
      acc[nt] = __builtin_amdgcn_mfma_f32_32x32x16_f16(a, bb, acc[nt], 0, 0, 0);
    }
  }

  _Float16* cb = cBH + (size_t)l * B * H;
  const int bbase = b0 + wave * 32 + 4 * hi32;
  const int hcol  = h0 + ln31;
#pragma unroll
  for (int nt = 0; nt < 4; ++nt) {
    const int h = hcol + nt * 32;
#pragma unroll
    for (int reg = 0; reg < 16; ++reg) {
      const int b = bbase + (reg & 3) + 8 * (reg >> 2);
      cb[(size_t)b * H + h] = (_Float16)acc[nt][reg];
    }
  }
}

// -------------------------------------------------------------------------
// k1sum: S[q][b][h] = sum over chunk q's l of c[l,b,h], fp32, via chained
// MFMA (no per-l reset -> the accumulator IS the sum). Same frag/D layout
// as k1 (verified), fp32 stores.
// -------------------------------------------------------------------------
__global__ __launch_bounds__(256, 4) void k1_sum(const _Float16* __restrict__ xT,
                                                 const _Float16* __restrict__ Wt,
                                                 float* __restrict__ S) {
  const int b0 = blockIdx.x * 128, h0 = blockIdx.y * 128, q = blockIdx.z;
  const int wave = threadIdx.x >> 6, lane = threadIdx.x & 63;
  const int ln31 = lane & 31, hi32 = lane >> 5;

  f32x16 acc[4];
#pragma unroll
  for (int nt = 0; nt < 4; ++nt)
#pragma unroll
    for (int r = 0; r < 16; ++r) acc[nt][r] = 0.f;

#pragma unroll 1
  for (int ll = 0; ll < NL; ++ll) {
    const int l = q * NL + ll;
    if (l >= L) break;
    const _Float16* Ap = xT + ((size_t)l * B + b0 + wave * 32 + ln31) * KP1 + hi32 * 8;
    const _Float16* Bp = Wt + ((size_t)l * H + h0 + ln31) * KP1 + hi32 * 8;
#pragma unroll
    for (int kt = 0; kt < 4; ++kt) {
      half8 a = *(const half8*)(Ap + kt * 16);
#pragma unroll
      for (int nt = 0; nt < 4; ++nt) {
        half8 bb = *(const half8*)(Bp + (size_t)nt * 32 * KP1 + kt * 16);
        acc[nt] = __builtin_amdgcn_mfma_f32_32x32x16_f16(a, bb, acc[nt], 0, 0, 0);
      }
    }
  }

  float* Sp = S + (size_t)q * B * H;
  const int bbase = b0 + wave * 32 + 4 * hi32;
  const int hcol  = h0 + ln31;
#pragma unroll
  for (int nt = 0; nt < 4; ++nt) {
    const int h = hcol + nt * 32;
#pragma unroll
    for (int reg = 0; reg < 16; ++reg) {
      const int b = bbase + (reg & 3) + 8 * (reg >> 2);
      Sp[(size_t)b * H + h] = acc[nt][reg];
    }
  }
}

// -------------------------------------------------------------------------
// kP: in-place exclusive prefix over the NQ chunk-sum planes per (b,h),
// with b_enc folded in: P[q] = benc + sum_{p<q} S[p]. float4 per thread,
// 4 planes of loads in flight per step.
// -------------------------------------------------------------------------
__device__ __forceinline__ float4 add4(float4 a, float4 b) {
  return (float4){a.x + b.x, a.y + b.y, a.z + b.z, a.w + b.w};
}
__global__ __launch_bounds__(256) void kP(float* __restrict__ S,
                                          const float* __restrict__ benc) {
  const int t = blockIdx.x * 256 + threadIdx.x;  // t < B*H/4
  const int h = (t * 4) & (H - 1);
  float4 run = *(const float4*)&benc[h];
  float4* p = (float4*)S;
  const size_t stride = (size_t)B * H / 4;
  size_t idx = (size_t)t;
#pragma unroll 1
  for (int g = 0; g < 15; ++g) {  // 60 planes in groups of 4
    float4 v0 = p[idx + 0 * stride];
    float4 v1 = p[idx + 1 * stride];
    float4 v2 = p[idx + 2 * stride];
    float4 v3 = p[idx + 3 * stride];
    p[idx + 0 * stride] = run; run = add4(run, v0);
    p[idx + 1 * stride] = run; run = add4(run, v1);
    p[idx + 2 * stride] = run; run = add4(run, v2);
    p[idx + 3 * stride] = run; run = add4(run, v3);
    idx += 4 * stride;
  }
  // remaining 3 planes (60, 61, 62)
  float4 v0 = p[idx + 0 * stride];
  float4 v1 = p[idx + 1 * stride];
  p[idx + 0 * stride] = run; run = add4(run, v0);
  p[idx + 1 * stride] = run; run = add4(run, v1);
  p[idx + 2 * stride] = run;
}

// -------------------------------------------------------------------------
// k23: fused scan + projection. NO LDS, NO barriers. Wave owns 16 b-rows x
// chunk q. State = running sum (fp32, A-frag layout: lane=b-row16,
// h=kt*32+quad*8+j -> 128 VGPR). Per l: proj via relu(state) A-frags +
// Vt B-frags (global, L2/L3), then state += c[l] (coalesced half8 loads).
// -------------------------------------------------------------------------
__global__ __launch_bounds__(256, 2) void k23(const _Float16* __restrict__ cBH,
                                              const float* __restrict__ P,
                                              const _Float16* __restrict__ Vt,
                                              const float* __restrict__ bmu,
                                              const float* __restrict__ bsg,
                                              const float* __restrict__ bpi,
                                              float* __restrict__ out) {
  const int q = blockIdx.y;
  const int wave = threadIdx.x >> 6, lane = threadIdx.x & 63;
  const int row16 = lane & 15, quad = lane >> 4;
  const int m0 = blockIdx.x * 64 + wave * 16;
  const int bRow = m0 + row16;

  // state init from exclusive chunk prefix (b_enc already folded in by kP)
  float st[16][8];
  const float* Pp = P + (size_t)q * B * H + (size_t)bRow * H + quad * 8;
#pragma unroll
  for (int kt = 0; kt < 16; ++kt) {
    float4 u0 = *(const float4*)(Pp + kt * 32);
    float4 u1 = *(const float4*)(Pp + kt * 32 + 4);
    st[kt][0] = u0.x; st[kt][1] = u0.y; st[kt][2] = u0.z; st[kt][3] = u0.w;
    st[kt][4] = u1.x; st[kt][5] = u1.y; st[kt][6] = u1.z; st[kt][7] = u1.w;
  }

#pragma unroll 1
  for (int ll = 0; ll < NL; ++ll) {
    const int l = q * NL + ll;
    if (l >= L) break;

    // projection: out[l, b-rows, :] = relu(state) @ Vt[l]
    f32x4 acc[3];
#pragma unroll
    for (int nt = 0; nt < 3; ++nt) acc[nt] = (f32x4){0.f, 0.f, 0.f, 0.f};
    const _Float16* Vb = Vt + (size_t)l * JP * KPV + (size_t)row16 * KPV + quad * 8;
#pragma unroll
    for (int kt = 0; kt < 16; ++kt) {
      half8 a;
#pragma unroll
      for (int j = 0; j < 8; ++j) a[j] = (_Float16)fmaxf(st[kt][j], 0.f);
      half8 f0 = *(const half8*)(Vb + kt * 32);
      half8 f1 = *(const half8*)(Vb + 16 * KPV + kt * 32);
      half8 f2 = *(const half8*)(Vb + 32 * KPV + kt * 32);
      acc[0] = __builtin_amdgcn_mfma_f32_16x16x32_f16(a, f0, acc[0], 0, 0, 0);
      acc[1] = __builtin_amdgcn_mfma_f32_16x16x32_f16(a, f1, acc[1], 0, 0, 0);
      acc[2] = __builtin_amdgcn_mfma_f32_16x16x32_f16(a, f2, acc[2], 0, 0, 0);
    }

    // state += c[l]  (same h-mapping as A-frags: coalesced half8 loads)
    const _Float16* cp = cBH + ((size_t)l * B + bRow) * H + quad * 8;
#pragma unroll
    for (int kt = 0; kt < 16; ++kt) {
      half8 cv = *(const half8*)(cp + kt * 32);
#pragma unroll
      for (int j = 0; j < 8; ++j) st[kt][j] += (float)cv[j];
    }

    // epilogue: D layout col(j)=lane&15, row(b)=quad*4+r
#pragma unroll
    for (int nt = 0; nt < 3; ++nt) {
      const int j = nt * 16 + row16;
      if (j < J) {
        const float bias = (j < O) ? bmu[l * O + j]
                         : (j < 2 * O) ? bsg[l * O + (j - O)]
                         : bpi[l * M + (j - 2 * O)];
#pragma unroll
        for (int r = 0; r < 4; ++r) {
          const int b = m0 + quad * 4 + r;
          out[((size_t)b * L + l) * J + j] = acc[nt][r] + bias;
        }
      }
    }
  }
}

extern "C" void kernel_launch(void* const* d_in, const int* in_sizes, int n_in,
                              void* d_out, int out_size, void* d_ws, size_t ws_size,
                              hipStream_t stream) {
  const float* inp  = (const float*)d_in[0];
  const float* z    = (const float*)d_in[1];
  const float* Wenc = (const float*)d_in[2];
  const float* benc = (const float*)d_in[3];
  const float* Vmu  = (const float*)d_in[4];
  const float* bmu  = (const float*)d_in[5];
  const float* Vsg  = (const float*)d_in[6];
  const float* bsg  = (const float*)d_in[7];
  const float* Vpi  = (const float*)d_in[8];
  const float* bpi  = (const float*)d_in[9];
  float* out = (float*)d_out;

  // Workspace: cBH 131.07 + xT 16.38 + Wt 32.77 + Vt 24.96 + S 33.03 = 238.2 MB
  char* ws = (char*)d_ws;
  _Float16* cBH = (_Float16*)ws;                            // [L][B][H] fp16
  _Float16* xT  = (_Float16*)(ws + 131072000);              // [L][B][64] fp16
  _Float16* Wt  = (_Float16*)(ws + 147456000);              // [L][H][64] fp16
  _Float16* Vt  = (_Float16*)(ws + 180224000);              // [L][48][520] fp16
  float*    S   = (float*)(ws + 205184000);                 // [NQ][B][H] fp32

  k0x<<<dim3(L), 256, 0, stream>>>(inp, z, xT);
  k0w<<<dim3(L), 256, 0, stream>>>(Wenc, Wt);
  k0v<<<dim3(L), 256, 0, stream>>>(Vmu, Vsg, Vpi, Vt);
  k1_c<<<dim3(B / 128, H / 128, L), 256, 0, stream>>>(xT, Wt, cBH);
  k1_sum<<<dim3(B / 128, H / 128, NQ), 256, 0, stream>>>(xT, Wt, S);
  kP<<<dim3((B * H / 4) / 256), 256, 0, stream>>>(S, benc);
  k23<<<dim3(B / 64, NQ), 256, 0, stream>>>(cBH, S, Vt, bmu, bsg, bpi, out);
}

// Round 7
// 359.564 us; speedup vs baseline: 1.0425x; 1.0425x over previous
//
#include <hip/hip_runtime.h>

// Problem constants (from reference)
constexpr int B = 256, L = 500, D = 3, C = 32, I = 35, H = 512, O = 15, M = 5, J = 35;
constexpr int KP1 = 64;  // k1 K-dim (I=35) zero-padded
constexpr int JP = 48;   // out-cols padded to 3 MFMA n-tiles
constexpr int KPV = 520; // padded K leading dim for Vt
constexpr int NQ = 63;   // l-chunks (8 l each; last chunk has 4)
constexpr int NL = 8;    // l per chunk
constexpr int CSP = 136; // Cs row stride in fp16 (mod-32-word offset 4 -> 2-way max)

typedef __attribute__((ext_vector_type(8))) _Float16 half8;  // MFMA A/B frag
typedef __attribute__((ext_vector_type(4))) _Float16 half4;
typedef __attribute__((ext_vector_type(4))) float f32x4;     // 16x16 C/D frag
typedef __attribute__((ext_vector_type(16))) float f32x16;   // 32x32 C/D frag

// -------------------------------------------------------------------------
// k0x: xT[l][b][k] fp16, K padded to 64 (zeros k>=35).
// -------------------------------------------------------------------------
__global__ __launch_bounds__(256) void k0x(const float* __restrict__ inp,
                                           const float* __restrict__ z,
                                           _Float16* __restrict__ xT) {
  const int l = blockIdx.x, tid = threadIdx.x;  // tid = b
  __shared__ _Float16 xs[B][38];
  const float* ip = inp + ((size_t)tid * L + l) * D;
  const float4* zp = (const float4*)(z + ((size_t)tid * L + l) * C);
  xs[tid][0] = (_Float16)ip[0];
  xs[tid][1] = (_Float16)ip[1];
  xs[tid][2] = (_Float16)ip[2];
#pragma unroll
  for (int q = 0; q < 8; ++q) {
    float4 v = zp[q];
    xs[tid][D + q * 4 + 0] = (_Float16)v.x;
    xs[tid][D + q * 4 + 1] = (_Float16)v.y;
    xs[tid][D + q * 4 + 2] = (_Float16)v.z;
    xs[tid][D + q * 4 + 3] = (_Float16)v.w;
  }
  __syncthreads();
  unsigned int* dst = (unsigned int*)(xT + (size_t)l * B * KP1);
  for (int f = tid; f < B * KP1 / 2; f += 256) {
    int b = f >> 5, k = (f & 31) * 2;
    unsigned int lo = (k < I)     ? *(const unsigned short*)&xs[b][k]     : 0u;
    unsigned int hi = (k + 1 < I) ? *(const unsigned short*)&xs[b][k + 1] : 0u;
    dst[f] = lo | (hi << 16);
  }
}

// -------------------------------------------------------------------------
// k0w: Wt[l][h][k] fp16 (K padded 64) from W_enc fp32 [l][i][h] (transpose).
// -------------------------------------------------------------------------
__global__ __launch_bounds__(256) void k0w(const float* __restrict__ W,
                                           _Float16* __restrict__ Wt) {
  const int l = blockIdx.x, tid = threadIdx.x;
  __shared__ _Float16 ws[H][37];
  for (int f = tid; f < I * H; f += 256) {
    int i = f >> 9, h = f & 511;
    ws[h][i] = (_Float16)W[((size_t)l * I + i) * H + h];
  }
  __syncthreads();
  unsigned int* dst = (unsigned int*)(Wt + (size_t)l * H * KP1);
  for (int f = tid; f < H * KP1 / 2; f += 256) {
    int h = f >> 5, k = (f & 31) * 2;
    unsigned int lo = (k < I)     ? *(const unsigned short*)&ws[h][k]     : 0u;
    unsigned int hi = (k + 1 < I) ? *(const unsigned short*)&ws[h][k + 1] : 0u;
    dst[f] = lo | (hi << 16);
  }
}

// -------------------------------------------------------------------------
// k0v: Vt[l][j][k] fp16 [L][48][520]. LDS transpose, linear uint4 writes.
// -------------------------------------------------------------------------
__global__ __launch_bounds__(256) void k0v(const float* __restrict__ Vmu,
                                           const float* __restrict__ Vsg,
                                           const float* __restrict__ Vpi,
                                           _Float16* __restrict__ Vt) {
  const int l = blockIdx.x, tid = threadIdx.x;
  __shared__ __align__(16) _Float16 Vs[JP * KPV];  // 49,920 B
  for (int f = tid; f < (JP * KPV) / 8; f += 256) ((uint4*)Vs)[f] = (uint4){0, 0, 0, 0};
  __syncthreads();
  const float* vm = Vmu + (size_t)l * H * O;
  const float* vs = Vsg + (size_t)l * H * O;
  const float* vp = Vpi + (size_t)l * H * M;
  for (int idx = tid; idx < H * O; idx += 256) {
    int k = idx / O, j = idx - k * O;
    Vs[j * KPV + k]       = (_Float16)vm[idx];
    Vs[(O + j) * KPV + k] = (_Float16)vs[idx];
  }
  for (int idx = tid; idx < H * M; idx += 256) {
    int k = idx / M, j = idx - k * M;
    Vs[(2 * O + j) * KPV + k] = (_Float16)vp[idx];
  }
  __syncthreads();
  uint4* dst = (uint4*)(Vt + (size_t)l * JP * KPV);
  for (int f = tid; f < (JP * KPV) / 8; f += 256) dst[f] = ((const uint4*)Vs)[f];
}

// -------------------------------------------------------------------------
// k1sum: S[q][b][h] = sum over chunk q's l of c[l,b,h], fp32, chained MFMA.
// Re-tiled vs round 6: 1008 blocks (64b x 128h x NQ), wave = 32b x 64h.
// -------------------------------------------------------------------------
__global__ __launch_bounds__(256, 4) void k1_sum(const _Float16* __restrict__ xT,
                                                 const _Float16* __restrict__ Wt,
                                                 float* __restrict__ S) {
  const int b0 = blockIdx.x * 64, h0 = blockIdx.y * 128, q = blockIdx.z;
  const int wv = threadIdx.x >> 6, lane = threadIdx.x & 63;
  const int ln31 = lane & 31, hi32 = lane >> 5;
  const int bb = b0 + (wv & 1) * 32;
  const int hh = h0 + (wv >> 1) * 64;

  f32x16 acc[2];
#pragma unroll
  for (int nt = 0; nt < 2; ++nt)
#pragma unroll
    for (int r = 0; r < 16; ++r) acc[nt][r] = 0.f;

#pragma unroll 1
  for (int ll = 0; ll < NL; ++ll) {
    const int l = q * NL + ll;
    if (l >= L) break;
    const _Float16* Ap = xT + ((size_t)l * B + bb + ln31) * KP1 + hi32 * 8;
    const _Float16* Bp = Wt + ((size_t)l * H + hh + ln31) * KP1 + hi32 * 8;
#pragma unroll
    for (int kt = 0; kt < 4; ++kt) {
      half8 a = *(const half8*)(Ap + kt * 16);
#pragma unroll
      for (int nt = 0; nt < 2; ++nt) {
        half8 w = *(const half8*)(Bp + (size_t)nt * 32 * KP1 + kt * 16);
        acc[nt] = __builtin_amdgcn_mfma_f32_32x32x16_f16(a, w, acc[nt], 0, 0, 0);
      }
    }
  }

  float* Sp = S + (size_t)q * B * H;
#pragma unroll
  for (int nt = 0; nt < 2; ++nt) {
    const int h = hh + nt * 32 + ln31;
#pragma unroll
    for (int reg = 0; reg < 16; ++reg) {
      const int b = bb + (reg & 3) + 8 * (reg >> 2) + 4 * hi32;
      Sp[(size_t)b * H + h] = acc[nt][reg];
    }
  }
}

// -------------------------------------------------------------------------
// kP: in-place exclusive prefix over NQ chunk-sum planes per (b,h), b_enc
// folded in. 512 blocks, 1 fp32/thread, 7 loads in flight (9 groups x 7).
// -------------------------------------------------------------------------
__global__ __launch_bounds__(256) void kP(float* __restrict__ S,
                                          const float* __restrict__ benc) {
  const int t = blockIdx.x * 256 + threadIdx.x;  // t < B*H
  float run = benc[t & (H - 1)];
  const size_t stride = (size_t)B * H;
  size_t idx = (size_t)t;
#pragma unroll 1
  for (int g = 0; g < 9; ++g) {  // 63 planes = 9 x 7
    float v[7];
#pragma unroll
    for (int j = 0; j < 7; ++j) v[j] = S[idx + j * stride];
#pragma unroll
    for (int j = 0; j < 7; ++j) {
      S[idx + j * stride] = run;
      run += v[j];
    }
    idx += 7 * stride;
  }
}

// -------------------------------------------------------------------------
// k23: FULLY fused c-compute + scan + projection. cBH eliminated.
// Block = 16 b-rows x chunk q; 4 waves split the H=512 K-dim (128 h each;
// state = 32 VGPR fp32). Per l:
//   (1) c-tile via MFMA (A=Wt m=h, B=xT n=b -> D col=b matches state lanes),
//       written to wave-PRIVATE LDS (fp16, no barrier needed),
//   (2) proj partial via relu(state) A-frags x Vt B-frags (12 MFMAs),
//   (3) cross-wave LDS reduce of the 3 n-tile partials + bias + store,
//   (4) state += c (LDS read back in A-frag layout).
// -------------------------------------------------------------------------
__global__ __launch_bounds__(256, 4) void k23(const _Float16* __restrict__ xT,
                                              const _Float16* __restrict__ Wt,
                                              const float* __restrict__ P,
                                              const _Float16* __restrict__ Vt,
                                              const float* __restrict__ bmu,
                                              const float* __restrict__ bsg,
                                              const float* __restrict__ bpi,
                                              float* __restrict__ out) {
  const int bg = blockIdx.x;  // 16 b-rows per block
  const int q  = blockIdx.y;
  const int wv = threadIdx.x >> 6, lane = threadIdx.x & 63;
  const int row16 = lane & 15, quad = lane >> 4;
  const int bRow = bg * 16 + row16;
  const int hW = wv * 128;    // this wave's h/K slice

  __shared__ __align__(16) _Float16 Cs[4][16][CSP];  // 17,408 B (wave-private)
  __shared__ __align__(16) float red[4][64][20];     // 20,480 B

  // state init from exclusive chunk prefix (b_enc folded in by kP)
  float st[4][8];
  {
    const float* Pp = P + ((size_t)q * B + bRow) * H + hW + quad * 8;
#pragma unroll
    for (int g = 0; g < 4; ++g) {
      float4 u0 = *(const float4*)(Pp + g * 32);
      float4 u1 = *(const float4*)(Pp + g * 32 + 4);
      st[g][0] = u0.x; st[g][1] = u0.y; st[g][2] = u0.z; st[g][3] = u0.w;
      st[g][4] = u1.x; st[g][5] = u1.y; st[g][6] = u1.z; st[g][7] = u1.w;
    }
  }

#pragma unroll 1
  for (int ll = 0; ll < NL; ++ll) {
    const int l = q * NL + ll;
    if (l >= L) break;

    // (1) c-tile for (16 b, this wave's 128 h) -> Cs[wv]
    const _Float16* xb = xT + ((size_t)l * B + bRow) * KP1 + quad * 8;
    half8 bx0 = *(const half8*)(xb);
    half8 bx1 = *(const half8*)(xb + 32);
    const _Float16* Wb = Wt + ((size_t)l * H + hW + row16) * KP1 + quad * 8;
#pragma unroll
    for (int t = 0; t < 8; ++t) {
      half8 aw0 = *(const half8*)(Wb + (size_t)t * 16 * KP1);
      half8 aw1 = *(const half8*)(Wb + (size_t)t * 16 * KP1 + 32);
      f32x4 dc = (f32x4){0.f, 0.f, 0.f, 0.f};
      dc = __builtin_amdgcn_mfma_f32_16x16x32_f16(aw0, bx0, dc, 0, 0, 0);
      dc = __builtin_amdgcn_mfma_f32_16x16x32_f16(aw1, bx1, dc, 0, 0, 0);
      // D: col(b)=lane&15=row16, row(h)=t*16+quad*4+r
      half4 cc;
#pragma unroll
      for (int r = 0; r < 4; ++r) cc[r] = (_Float16)dc[r];
      *(half4*)&Cs[wv][row16][t * 16 + quad * 4] = cc;
    }

    // (2) proj partial over this wave's K-slice
    f32x4 acc[3];
#pragma unroll
    for (int nt = 0; nt < 3; ++nt) acc[nt] = (f32x4){0.f, 0.f, 0.f, 0.f};
    const _Float16* Vb = Vt + (size_t)l * JP * KPV + (size_t)row16 * KPV + hW + quad * 8;
#pragma unroll
    for (int g = 0; g < 4; ++g) {
      half8 a;
#pragma unroll
      for (int j = 0; j < 8; ++j) a[j] = (_Float16)fmaxf(st[g][j], 0.f);
      half8 f0 = *(const half8*)(Vb + g * 32);
      half8 f1 = *(const half8*)(Vb + 16 * KPV + g * 32);
      half8 f2 = *(const half8*)(Vb + 32 * KPV + g * 32);
      acc[0] = __builtin_amdgcn_mfma_f32_16x16x32_f16(a, f0, acc[0], 0, 0, 0);
      acc[1] = __builtin_amdgcn_mfma_f32_16x16x32_f16(a, f1, acc[1], 0, 0, 0);
      acc[2] = __builtin_amdgcn_mfma_f32_16x16x32_f16(a, f2, acc[2], 0, 0, 0);
    }

    // (4, early) state += c: read back own wave's slice in A-frag layout
#pragma unroll
    for (int g = 0; g < 4; ++g) {
      half8 cv = *(const half8*)&Cs[wv][row16][g * 32 + quad * 8];
#pragma unroll
      for (int j = 0; j < 8; ++j) st[g][j] += (float)cv[j];
    }

    // (3) cross-wave reduce of proj partials, bias, store
    *(f32x4*)&red[wv][lane][0] = acc[0];
    *(f32x4*)&red[wv][lane][4] = acc[1];
    *(f32x4*)&red[wv][lane][8] = acc[2];
    __syncthreads();
    if (wv < 3) {
      const int nt = wv;
      f32x4 t0 = *(const f32x4*)&red[0][lane][nt * 4];
      f32x4 t1 = *(const f32x4*)&red[1][lane][nt * 4];
      f32x4 t2 = *(const f32x4*)&red[2][lane][nt * 4];
      f32x4 t3 = *(const f32x4*)&red[3][lane][nt * 4];
      f32x4 tot = t0 + t1 + t2 + t3;
      const int j = nt * 16 + row16;
      if (j < J) {
        const float bias = (j < O) ? bmu[l * O + j]
                         : (j < 2 * O) ? bsg[l * O + (j - O)]
                         : bpi[l * M + (j - 2 * O)];
#pragma unroll
        for (int r = 0; r < 4; ++r) {
          const int b = bg * 16 + quad * 4 + r;
          out[((size_t)b * L + l) * J + j] = tot[r] + bias;
        }
      }
    }
    __syncthreads();
  }
}

extern "C" void kernel_launch(void* const* d_in, const int* in_sizes, int n_in,
                              void* d_out, int out_size, void* d_ws, size_t ws_size,
                              hipStream_t stream) {
  const float* inp  = (const float*)d_in[0];
  const float* z    = (const float*)d_in[1];
  const float* Wenc = (const float*)d_in[2];
  const float* benc = (const float*)d_in[3];
  const float* Vmu  = (const float*)d_in[4];
  const float* bmu  = (const float*)d_in[5];
  const float* Vsg  = (const float*)d_in[6];
  const float* bsg  = (const float*)d_in[7];
  const float* Vpi  = (const float*)d_in[8];
  const float* bpi  = (const float*)d_in[9];
  float* out = (float*)d_out;

  // Workspace: xT 16.38 + Wt 32.77 + Vt 24.96 + S 33.03 = 107.1 MB
  char* ws = (char*)d_ws;
  _Float16* xT = (_Float16*)ws;                  // [L][B][64] fp16
  _Float16* Wt = (_Float16*)(ws + 16384000);     // [L][H][64] fp16
  _Float16* Vt = (_Float16*)(ws + 49152000);     // [L][48][520] fp16
  float*    S  = (float*)(ws + 74112000);        // [NQ][B][H] fp32

  k0x<<<dim3(L), 256, 0, stream>>>(inp, z, xT);
  k0w<<<dim3(L), 256, 0, stream>>>(Wenc, Wt);
  k0v<<<dim3(L), 256, 0, stream>>>(Vmu, Vsg, Vpi, Vt);
  k1_sum<<<dim3(B / 64, H / 128, NQ), 256, 0, stream>>>(xT, Wt, S);
  kP<<<dim3((B * H) / 256), 256, 0, stream>>>(S, benc);
  k23<<<dim3(B / 16, NQ), 256, 0, stream>>>(xT, Wt, S, Vt, bmu, bsg, bpi, out);
}

// Round 8
// 345.504 us; speedup vs baseline: 1.0849x; 1.0407x over previous
//
#include <hip/hip_runtime.h>

// Problem constants (from reference)
constexpr int B = 256, L = 500, D = 3, C = 32, I = 35, H = 512, O = 15, M = 5, J = 35;
constexpr int KP1 = 64;  // k1 K-dim (I=35) zero-padded
constexpr int JP = 48;   // out-cols padded to 3 MFMA n-tiles
constexpr int KV = 512;  // Vt leading dim (global mem, no bank concerns)
constexpr int NQ = 63;   // l-chunks (8 l each; last chunk has 4)
constexpr int NL = 8;    // l per chunk

typedef __attribute__((ext_vector_type(8))) _Float16 half8;  // MFMA A/B frag
typedef __attribute__((ext_vector_type(4))) float f32x4;     // 16x16 C/D frag
typedef __attribute__((ext_vector_type(16))) float f32x16;   // 32x32 C/D frag

// Vt column permutation: A-frag element j of proj step g on lane quad holds
// state st[2g+(j>>2)][j&3] = h_local (2g+(j>>2))*16 + quad*4 + (j&3).
// So Vt col p = g*32+quad*8+j must hold V row h_local = t*16+qd*4+r where
// t=2g+(j>>2), qd=quad, r=j&3.  Inverse (h_local -> p):
//   t=hl>>4, qd=(hl>>2)&3, r=hl&3; p = ((t>>1)<<5)|(qd<<3)|(((t&1)<<2)|r)
__device__ __forceinline__ int vperm(int h) {
  int hl = h & 127;
  int t = hl >> 4, qd = (hl >> 2) & 3, r = hl & 3;
  return (h & ~127) | ((t >> 1) << 5) | (qd << 3) | ((t & 1) << 2) | r;
}

// -------------------------------------------------------------------------
// k0: ALL input prep in one kernel (was k0x+k0w+k0v). One block per l.
//   A: xT[l][b][k] fp16 (K pad 64)       B: Wt[l][h][k] fp16 (transpose)
//   C: Vt[l][j][p] fp16 (transpose + perm cols + zero-pad rows 35..47)
// -------------------------------------------------------------------------
__global__ __launch_bounds__(256) void k0(const float* __restrict__ inp,
                                          const float* __restrict__ z,
                                          const float* __restrict__ W,
                                          const float* __restrict__ Vmu,
                                          const float* __restrict__ Vsg,
                                          const float* __restrict__ Vpi,
                                          _Float16* __restrict__ xT,
                                          _Float16* __restrict__ Wt,
                                          _Float16* __restrict__ Vt) {
  const int l = blockIdx.x, tid = threadIdx.x;
  __shared__ __align__(16) char smem[49152];

  // ---- stage A: xT ----
  {
    _Float16(*xs)[38] = (_Float16(*)[38])smem;
    const float* ip = inp + ((size_t)tid * L + l) * D;
    const float4* zp = (const float4*)(z + ((size_t)tid * L + l) * C);
    xs[tid][0] = (_Float16)ip[0];
    xs[tid][1] = (_Float16)ip[1];
    xs[tid][2] = (_Float16)ip[2];
#pragma unroll
    for (int qq = 0; qq < 8; ++qq) {
      float4 v = zp[qq];
      xs[tid][D + qq * 4 + 0] = (_Float16)v.x;
      xs[tid][D + qq * 4 + 1] = (_Float16)v.y;
      xs[tid][D + qq * 4 + 2] = (_Float16)v.z;
      xs[tid][D + qq * 4 + 3] = (_Float16)v.w;
    }
    __syncthreads();
    unsigned int* dst = (unsigned int*)(xT + (size_t)l * B * KP1);
    for (int f = tid; f < B * KP1 / 2; f += 256) {
      int b = f >> 5, k = (f & 31) * 2;
      unsigned int lo = (k < I)     ? *(const unsigned short*)&xs[b][k]     : 0u;
      unsigned int hi = (k + 1 < I) ? *(const unsigned short*)&xs[b][k + 1] : 0u;
      dst[f] = lo | (hi << 16);
    }
    __syncthreads();
  }

  // ---- stage B: Wt ----
  {
    _Float16(*wsm)[37] = (_Float16(*)[37])smem;
    for (int f = tid; f < I * H; f += 256) {
      int i = f >> 9, h = f & 511;
      wsm[h][i] = (_Float16)W[((size_t)l * I + i) * H + h];
    }
    __syncthreads();
    unsigned int* dst = (unsigned int*)(Wt + (size_t)l * H * KP1);
    for (int f = tid; f < H * KP1 / 2; f += 256) {
      int h = f >> 5, k = (f & 31) * 2;
      unsigned int lo = (k < I)     ? *(const unsigned short*)&wsm[h][k]     : 0u;
      unsigned int hi = (k + 1 < I) ? *(const unsigned short*)&wsm[h][k + 1] : 0u;
      dst[f] = lo | (hi << 16);
    }
    __syncthreads();
  }

  // ---- stage C: Vt (permuted cols) ----
  {
    _Float16(*vs)[KV] = (_Float16(*)[KV])smem;
    // zero the n-pad rows only (rows < J are fully overwritten below)
    for (int f = tid; f < (JP - J) * KV; f += 256) {
      int j = f / KV, k = f - j * KV;
      vs[J + j][k] = (_Float16)0.f;
    }
    const float* vm = Vmu + (size_t)l * H * O;
    const float* vg = Vsg + (size_t)l * H * O;
    const float* vp = Vpi + (size_t)l * H * M;
    for (int idx = tid; idx < H * O; idx += 256) {
      int h = idx / O, j = idx - h * O;
      int p = vperm(h);
      vs[j][p]     = (_Float16)vm[idx];
      vs[O + j][p] = (_Float16)vg[idx];
    }
    for (int idx = tid; idx < H * M; idx += 256) {
      int h = idx / M, j = idx - h * M;
      vs[2 * O + j][vperm(h)] = (_Float16)vp[idx];
    }
    __syncthreads();
    uint4* dst = (uint4*)(Vt + (size_t)l * JP * KV);
    for (int f = tid; f < (JP * KV) / 8; f += 256) dst[f] = ((const uint4*)vs)[f];
  }
}

// -------------------------------------------------------------------------
// k1sum: S[q][b][h] = sum over chunk q's l of c[l,b,h], fp32, chained MFMA.
// XCD-swizzled flat grid: all 16 blocks of a chunk share one XCD's L2.
// -------------------------------------------------------------------------
__global__ __launch_bounds__(256, 4) void k1_sum(const _Float16* __restrict__ xT,
                                                 const _Float16* __restrict__ Wt,
                                                 float* __restrict__ S) {
  const int x = blockIdx.x;
  const int s = x & 7, rr = x >> 3;
  const int sub = rr & 15, qh = rr >> 4;
  const int q = qh * 8 + s;
  if (q >= NQ) return;
  const int b0 = (sub & 3) * 64, h0 = (sub >> 2) * 128;
  const int wv = threadIdx.x >> 6, lane = threadIdx.x & 63;
  const int ln31 = lane & 31, hi32 = lane >> 5;
  const int bb = b0 + (wv & 1) * 32;
  const int hh = h0 + (wv >> 1) * 64;

  f32x16 acc[2];
#pragma unroll
  for (int nt = 0; nt < 2; ++nt)
#pragma unroll
    for (int r = 0; r < 16; ++r) acc[nt][r] = 0.f;

#pragma unroll 1
  for (int ll = 0; ll < NL; ++ll) {
    const int l = q * NL + ll;
    if (l >= L) break;
    const _Float16* Ap = xT + ((size_t)l * B + bb + ln31) * KP1 + hi32 * 8;
    const _Float16* Bp = Wt + ((size_t)l * H + hh + ln31) * KP1 + hi32 * 8;
#pragma unroll
    for (int kt = 0; kt < 4; ++kt) {
      half8 a = *(const half8*)(Ap + kt * 16);
#pragma unroll
      for (int nt = 0; nt < 2; ++nt) {
        half8 w = *(const half8*)(Bp + (size_t)nt * 32 * KP1 + kt * 16);
        acc[nt] = __builtin_amdgcn_mfma_f32_32x32x16_f16(a, w, acc[nt], 0, 0, 0);
      }
    }
  }

  float* Sp = S + (size_t)q * B * H;
#pragma unroll
  for (int nt = 0; nt < 2; ++nt) {
    const int h = hh + nt * 32 + ln31;
#pragma unroll
    for (int reg = 0; reg < 16; ++reg) {
      const int b = bb + (reg & 3) + 8 * (reg >> 2) + 4 * hi32;
      Sp[(size_t)b * H + h] = acc[nt][reg];
    }
  }
}

// -------------------------------------------------------------------------
// kP: in-place exclusive prefix over NQ chunk-sum planes per (b,h), b_enc
// folded in. 512 blocks, 7 loads in flight per group.
// -------------------------------------------------------------------------
__global__ __launch_bounds__(256) void kP(float* __restrict__ S,
                                          const float* __restrict__ benc) {
  const int t = blockIdx.x * 256 + threadIdx.x;  // t < B*H
  float run = benc[t & (H - 1)];
  const size_t stride = (size_t)B * H;
  size_t idx = (size_t)t;
#pragma unroll 1
  for (int g = 0; g < 9; ++g) {  // 63 planes = 9 x 7
    float v[7];
#pragma unroll
    for (int j = 0; j < 7; ++j) v[j] = S[idx + j * stride];
#pragma unroll
    for (int j = 0; j < 7; ++j) {
      S[idx + j * stride] = run;
      run += v[j];
    }
    idx += 7 * stride;
  }
}

// -------------------------------------------------------------------------
// k23: fused c-compute + scan + projection, NO c-LDS round-trip.
// Block = 16 b x chunk q; 4 waves split H (128 h each). State st[t][r]
// (lane=b=row16, h = hW + t*16 + quad*4 + r) IS the c-MFMA D-layout ->
// "st += c" is pure register adds. Proj A-frags read st in permuted order
// matched by Vt's column permutation. One barrier per l (dbuf reduce).
// XCD-swizzled so a chunk's 16 blocks share one XCD's L2.
// -------------------------------------------------------------------------
__global__ __launch_bounds__(256, 4) void k23(const _Float16* __restrict__ xT,
                                              const _Float16* __restrict__ Wt,
                                              const float* __restrict__ P,
                                              const _Float16* __restrict__ Vt,
                                              const float* __restrict__ bmu,
                                              const float* __restrict__ bsg,
                                              const float* __restrict__ bpi,
                                              float* __restrict__ out) {
  const int x = blockIdx.x;
  const int s = x & 7, rr = x >> 3;
  const int bg = rr & 15, qh = rr >> 4;
  const int q = qh * 8 + s;
  if (q >= NQ) return;
  const int wv = threadIdx.x >> 6, lane = threadIdx.x & 63;
  const int row16 = lane & 15, quad = lane >> 4;
  const int bRow = bg * 16 + row16;
  const int hW = wv * 128;

  __shared__ float red[2][4][64][13];  // stride-13 rows: conflict-free

  // state init from exclusive chunk prefix (b_enc folded in by kP)
  float st[8][4];
  {
    const float* Pp = P + ((size_t)q * B + bRow) * H + hW + quad * 4;
#pragma unroll
    for (int t = 0; t < 8; ++t) {
      float4 u = *(const float4*)(Pp + t * 16);
      st[t][0] = u.x; st[t][1] = u.y; st[t][2] = u.z; st[t][3] = u.w;
    }
  }

#pragma unroll 1
  for (int ll = 0; ll < NL; ++ll) {
    const int l = q * NL + ll;
    if (l >= L) break;

    // (1) projection partial from CURRENT state (exclusive scan semantics)
    f32x4 acc[3];
#pragma unroll
    for (int nt = 0; nt < 3; ++nt) acc[nt] = (f32x4){0.f, 0.f, 0.f, 0.f};
    const _Float16* Vb = Vt + ((size_t)l * JP + row16) * KV + hW + quad * 8;
#pragma unroll
    for (int g = 0; g < 4; ++g) {
      half8 a;
#pragma unroll
      for (int j = 0; j < 8; ++j)
        a[j] = (_Float16)fmaxf(st[2 * g + (j >> 2)][j & 3], 0.f);
      half8 f0 = *(const half8*)(Vb + g * 32);
      half8 f1 = *(const half8*)(Vb + 16 * KV + g * 32);
      half8 f2 = *(const half8*)(Vb + 32 * KV + g * 32);
      acc[0] = __builtin_amdgcn_mfma_f32_16x16x32_f16(a, f0, acc[0], 0, 0, 0);
      acc[1] = __builtin_amdgcn_mfma_f32_16x16x32_f16(a, f1, acc[1], 0, 0, 0);
      acc[2] = __builtin_amdgcn_mfma_f32_16x16x32_f16(a, f2, acc[2], 0, 0, 0);
    }

    // (2) c-tile via MFMA; D-layout == state layout -> direct register adds
    const _Float16* xb = xT + ((size_t)l * B + bRow) * KP1 + quad * 8;
    half8 bx0 = *(const half8*)(xb);
    half8 bx1 = *(const half8*)(xb + 32);
    const _Float16* Wb = Wt + ((size_t)l * H + hW + row16) * KP1 + quad * 8;
#pragma unroll
    for (int t = 0; t < 8; ++t) {
      half8 aw0 = *(const half8*)(Wb + (size_t)t * 16 * KP1);
      half8 aw1 = *(const half8*)(Wb + (size_t)t * 16 * KP1 + 32);
      f32x4 dc = (f32x4){0.f, 0.f, 0.f, 0.f};
      dc = __builtin_amdgcn_mfma_f32_16x16x32_f16(aw0, bx0, dc, 0, 0, 0);
      dc = __builtin_amdgcn_mfma_f32_16x16x32_f16(aw1, bx1, dc, 0, 0, 0);
#pragma unroll
      for (int r = 0; r < 4; ++r) st[t][r] += dc[r];
    }

    // (3) cross-wave reduce (double-buffered -> ONE barrier per l)
    const int p = ll & 1;
#pragma unroll
    for (int nt = 0; nt < 3; ++nt)
#pragma unroll
      for (int r = 0; r < 4; ++r) red[p][wv][lane][nt * 4 + r] = acc[nt][r];
    __syncthreads();
    if (wv < 3) {
      const int nt = wv;
      const int j = nt * 16 + row16;
      f32x4 tot;
#pragma unroll
      for (int r = 0; r < 4; ++r)
        tot[r] = red[p][0][lane][nt * 4 + r] + red[p][1][lane][nt * 4 + r] +
                 red[p][2][lane][nt * 4 + r] + red[p][3][lane][nt * 4 + r];
      if (j < J) {
        const float bias = (j < O) ? bmu[l * O + j]
                         : (j < 2 * O) ? bsg[l * O + (j - O)]
                         : bpi[l * M + (j - 2 * O)];
#pragma unroll
        for (int r = 0; r < 4; ++r) {
          const int b = bg * 16 + quad * 4 + r;
          out[((size_t)b * L + l) * J + j] = tot[r] + bias;
        }
      }
    }
  }
}

extern "C" void kernel_launch(void* const* d_in, const int* in_sizes, int n_in,
                              void* d_out, int out_size, void* d_ws, size_t ws_size,
                              hipStream_t stream) {
  const float* inp  = (const float*)d_in[0];
  const float* z    = (const float*)d_in[1];
  const float* Wenc = (const float*)d_in[2];
  const float* benc = (const float*)d_in[3];
  const float* Vmu  = (const float*)d_in[4];
  const float* bmu  = (const float*)d_in[5];
  const float* Vsg  = (const float*)d_in[6];
  const float* bsg  = (const float*)d_in[7];
  const float* Vpi  = (const float*)d_in[8];
  const float* bpi  = (const float*)d_in[9];
  float* out = (float*)d_out;

  // Workspace: xT 16.38 + Wt 32.77 + Vt 24.58 + S 33.03 = 106.8 MB
  char* ws = (char*)d_ws;
  _Float16* xT = (_Float16*)ws;                  // [L][B][64] fp16
  _Float16* Wt = (_Float16*)(ws + 16384000);     // [L][H][64] fp16
  _Float16* Vt = (_Float16*)(ws + 49152000);     // [L][48][512] fp16 (perm cols)
  float*    S  = (float*)(ws + 73728000);        // [NQ][B][H] fp32

  k0<<<dim3(L), 256, 0, stream>>>(inp, z, Wenc, Vmu, Vsg, Vpi, xT, Wt, Vt);
  k1_sum<<<dim3(1024), 256, 0, stream>>>(xT, Wt, S);
  kP<<<dim3((B * H) / 256), 256, 0, stream>>>(S, benc);
  k23<<<dim3(1024), 256, 0, stream>>>(xT, Wt, S, Vt, bmu, bsg, bpi, out);
}